// Round 1
// baseline (106302.063 us; speedup 1.0000x reference)
//
#include <hip/hip_runtime.h>
#include <cstdint>
#include <cstddef>

#define T_N 1024
#define B_N 64
#define I_N 512
#define H_N 512
#define G3  (3*H_N)
#define NBLK 256   // scan blocks; 256 CUs -> 1/CU, co-resident by construction
#define UPB  2     // hidden units per block (512/256)

// ---------------------------------------------------------------------------
// GEMM: C[m][n] = sum_k A[m][k]*W[n][k] + bias[n]   (A:[M,K], W:[N,K] row-major)
// ---------------------------------------------------------------------------
__global__ __launch_bounds__(256) void gemm_nt(
    const float* __restrict__ A,
    const float* __restrict__ W,
    const float* __restrict__ bias,
    float* __restrict__ C,
    int M, int N, int K)
{
  __shared__ float As[32][68];
  __shared__ float Ws[32][68];
  const int tid = threadIdx.x;
  const int n0 = blockIdx.x * 64;
  const int m0 = blockIdx.y * 64;
  const int ty = tid >> 4;   // 0..15
  const int tx = tid & 15;   // 0..15

  float acc[4][4];
#pragma unroll
  for (int i = 0; i < 4; ++i)
#pragma unroll
    for (int j = 0; j < 4; ++j) acc[i][j] = 0.f;

  for (int k0 = 0; k0 < K; k0 += 32) {
#pragma unroll
    for (int i = 0; i < 2; ++i) {
      int idx = tid + i * 256;     // 0..511
      int r   = idx >> 3;          // 0..63
      int c4  = idx & 7;           // 0..7
      float4 va = *(const float4*)(A + (size_t)(m0 + r) * K + k0 + c4 * 4);
      As[c4*4+0][r] = va.x; As[c4*4+1][r] = va.y;
      As[c4*4+2][r] = va.z; As[c4*4+3][r] = va.w;
      float4 vw = *(const float4*)(W + (size_t)(n0 + r) * K + k0 + c4 * 4);
      Ws[c4*4+0][r] = vw.x; Ws[c4*4+1][r] = vw.y;
      Ws[c4*4+2][r] = vw.z; Ws[c4*4+3][r] = vw.w;
    }
    __syncthreads();
#pragma unroll
    for (int k = 0; k < 32; ++k) {
      float4 a = *(const float4*)&As[k][ty * 4];
      float4 w = *(const float4*)&Ws[k][tx * 4];
      acc[0][0] += a.x*w.x; acc[0][1] += a.x*w.y; acc[0][2] += a.x*w.z; acc[0][3] += a.x*w.w;
      acc[1][0] += a.y*w.x; acc[1][1] += a.y*w.y; acc[1][2] += a.y*w.z; acc[1][3] += a.y*w.w;
      acc[2][0] += a.z*w.x; acc[2][1] += a.z*w.y; acc[2][2] += a.z*w.z; acc[2][3] += a.z*w.w;
      acc[3][0] += a.w*w.x; acc[3][1] += a.w*w.y; acc[3][2] += a.w*w.z; acc[3][3] += a.w*w.w;
    }
    __syncthreads();
  }

  float4 bv = *(const float4*)(bias + n0 + tx * 4);
#pragma unroll
  for (int i = 0; i < 4; ++i) {
    int row = m0 + ty * 4 + i;
    float4 o;
    o.x = acc[i][0] + bv.x; o.y = acc[i][1] + bv.y;
    o.z = acc[i][2] + bv.z; o.w = acc[i][3] + bv.w;
    *(float4*)(C + (size_t)row * N + n0 + tx * 4) = o;
  }
}

// ---------------------------------------------------------------------------
// grid barrier (device-scope, sense via generation counter)
// ---------------------------------------------------------------------------
__device__ __forceinline__ void gbar(int* cnt, int* gen, int nb)
{
  __syncthreads();
  if (threadIdx.x == 0) {
    __threadfence();
    int g = __hip_atomic_load(gen, __ATOMIC_RELAXED, __HIP_MEMORY_SCOPE_AGENT);
    if (__hip_atomic_fetch_add(cnt, 1, __ATOMIC_ACQ_REL, __HIP_MEMORY_SCOPE_AGENT) == nb - 1) {
      __hip_atomic_store(cnt, 0, __ATOMIC_RELAXED, __HIP_MEMORY_SCOPE_AGENT);
      __hip_atomic_fetch_add(gen, 1, __ATOMIC_ACQ_REL, __HIP_MEMORY_SCOPE_AGENT);
    } else {
      while (__hip_atomic_load(gen, __ATOMIC_ACQUIRE, __HIP_MEMORY_SCOPE_AGENT) == g) {
        __builtin_amdgcn_s_sleep(2);
      }
    }
    __threadfence();
  }
  __syncthreads();
}

__device__ __forceinline__ float sigm_(float x) { return 1.f / (1.f + __expf(-x)); }

// ---------------------------------------------------------------------------
// Persistent GRU scan for one layer.
// Block b owns hidden units j0 = 2b, 2b+1 -> w_hh rows {q*H + j0 + u} in LDS.
// Per step: stage h (4 chunks of 128 k) into swizzled LDS, k-split 4-way,
// LDS-reduce, gates on tid<64, one grid barrier.
// ---------------------------------------------------------------------------
__global__ __launch_bounds__(256) void gru_scan(
    const float* __restrict__ gx,     // [T][B][3H] (b_ih already added)
    const float* __restrict__ h0src,  // [B][H]
    const float* __restrict__ w_hh,   // [3H][H]
    const float* __restrict__ b_hh,   // [3H]
    float* __restrict__ out,          // [T][B][H]
    float* __restrict__ hT,           // [B][H]
    float* __restrict__ hbuf,         // 2*[B][H] double buffer
    int* __restrict__ bar)
{
  __shared__ float4 wl4[6 * 128];   // 12 KB  [g][k4], g=(q<<1)|u
  __shared__ float4 hl4[64 * 32];   // 32 KB  swizzled h chunk [b][k4^ (b&31)]
  const int tid = threadIdx.x;
  const int j0  = blockIdx.x * UPB;

  // persistent weight load (once per kernel)
#pragma unroll
  for (int it = 0; it < 3; ++it) {
    int idx = it * 256 + tid;         // 0..767
    int g   = idx >> 7;               // 0..5
    int k4  = idx & 127;
    int row = (g >> 1) * H_N + j0 + (g & 1);
    wl4[g * 128 + k4] = *(const float4*)(w_hh + (size_t)row * H_N + k4 * 4);
  }
  float2 br = {0,0}, bz = {0,0}, bn = {0,0};
  if (tid < 64) {
    br = *(const float2*)(b_hh + 0 * H_N + j0);
    bz = *(const float2*)(b_hh + 1 * H_N + j0);
    bn = *(const float2*)(b_hh + 2 * H_N + j0);
  }
  __syncthreads();

  const int b = tid & 63;
  const int s = tid >> 6;   // k-split 0..3

  for (int t = 0; t < T_N; ++t) {
    const float* hsrc = (t == 0) ? h0src : (hbuf + (size_t)(t & 1) * B_N * H_N);
    float* hdst = hbuf + (size_t)((t + 1) & 1) * B_N * H_N;

    float4 acc[6];
#pragma unroll
    for (int g = 0; g < 6; ++g) acc[g] = float4{0.f, 0.f, 0.f, 0.f};

    for (int c = 0; c < 4; ++c) {
      // stage chunk c (k in [c*128, c*128+128)) into LDS, coalesced + swizzled
#pragma unroll
      for (int it = 0; it < 8; ++it) {
        int idx = it * 256 + tid;     // 0..2047
        int bb  = idx >> 5;
        int k4  = idx & 31;
        float4 v = *(const float4*)(hsrc + (size_t)bb * H_N + c * 128 + k4 * 4);
        hl4[bb * 32 + (k4 ^ (bb & 31))] = v;
      }
      __syncthreads();
#pragma unroll
      for (int i = 0; i < 8; ++i) {
        int k4 = s * 8 + i;
        float4 h4 = hl4[b * 32 + (k4 ^ (b & 31))];
#pragma unroll
        for (int g = 0; g < 6; ++g) {
          float4 w4 = wl4[g * 128 + c * 32 + k4];
          acc[g].x += w4.x * h4.x; acc[g].y += w4.y * h4.y;
          acc[g].z += w4.z * h4.z; acc[g].w += w4.w * h4.w;
        }
      }
      __syncthreads();
    }

    // reduce the 4 k-split partials through LDS (reuse hl4)
    float* red = (float*)hl4;
#pragma unroll
    for (int g = 0; g < 6; ++g)
      red[g * 256 + b * 4 + s] = acc[g].x + acc[g].y + acc[g].z + acc[g].w;
    __syncthreads();

    if (tid < 64) {   // gate phase: thread = batch, both units
      float sr[2], sz[2], sn[2];
#pragma unroll
      for (int u = 0; u < 2; ++u) {
        float4 vr = *(float4*)&red[(0 * 2 + u) * 256 + tid * 4];
        float4 vz = *(float4*)&red[(1 * 2 + u) * 256 + tid * 4];
        float4 vn = *(float4*)&red[(2 * 2 + u) * 256 + tid * 4];
        sr[u] = vr.x + vr.y + vr.z + vr.w;
        sz[u] = vz.x + vz.y + vz.z + vz.w;
        sn[u] = vn.x + vn.y + vn.z + vn.w;
      }
      const size_t gxo = ((size_t)t * B_N + tid) * G3 + j0;
      float2 gr = *(const float2*)(gx + gxo + 0 * H_N);
      float2 gz = *(const float2*)(gx + gxo + 1 * H_N);
      float2 gn = *(const float2*)(gx + gxo + 2 * H_N);
      float2 hv = *(const float2*)(hsrc + (size_t)tid * H_N + j0);
      float hy[2];
#pragma unroll
      for (int u = 0; u < 2; ++u) {
        float ir = u ? gr.y : gr.x, iz = u ? gz.y : gz.x, in_ = u ? gn.y : gn.x;
        float hr = sr[u] + (u ? br.y : br.x);
        float hz = sz[u] + (u ? bz.y : bz.x);
        float hn = sn[u] + (u ? bn.y : bn.x);
        float r = sigm_(ir + hr);
        float z = sigm_(iz + hz);
        float n = tanhf(in_ + r * hn);
        float h = u ? hv.y : hv.x;
        hy[u] = n + z * (h - n);
      }
      float2 o = {hy[0], hy[1]};
      *(float2*)(hdst + (size_t)tid * H_N + j0) = o;
      *(float2*)(out + ((size_t)t * B_N + tid) * H_N + j0) = o;
      if (t == T_N - 1) *(float2*)(hT + (size_t)tid * H_N + j0) = o;
    }

    if (t + 1 < T_N) gbar(bar, bar + 1, NBLK);
  }
}

// ---------------------------------------------------------------------------
extern "C" void kernel_launch(void* const* d_in, const int* in_sizes, int n_in,
                              void* d_out, int out_size, void* d_ws, size_t ws_size,
                              hipStream_t stream)
{
  const float* x    = (const float*)d_in[0];
  const float* hx   = (const float*)d_in[1];
  const float* wih0 = (const float*)d_in[2];
  const float* whh0 = (const float*)d_in[3];
  const float* bih0 = (const float*)d_in[4];
  const float* bhh0 = (const float*)d_in[5];
  const float* wih1 = (const float*)d_in[6];
  const float* whh1 = (const float*)d_in[7];
  const float* bih1 = (const float*)d_in[8];
  const float* bhh1 = (const float*)d_in[9];
  float* out = (float*)d_out;   // [T*B*H] output, then [L*B*H] final hidden

  // workspace: gx [T*B*3H] | out0 [T*B*H] | hbuf 2*[B*H] | barrier
  float* gxb  = (float*)d_ws;
  float* out0 = gxb + (size_t)T_N * B_N * G3;
  float* hbuf = out0 + (size_t)T_N * B_N * H_N;
  int*   bar  = (int*)(hbuf + 2 * B_N * H_N);

  hipMemsetAsync(bar, 0, 16, stream);

  dim3 gg(G3 / 64, (T_N * B_N) / 64);

  // layer 0
  gemm_nt<<<gg, 256, 0, stream>>>(x, wih0, bih0, gxb, T_N * B_N, G3, I_N);
  gru_scan<<<NBLK, 256, 0, stream>>>(gxb, hx, whh0, bhh0, out0,
                                     out + (size_t)T_N * B_N * H_N, hbuf, bar);
  // layer 1
  gemm_nt<<<gg, 256, 0, stream>>>(out0, wih1, bih1, gxb, T_N * B_N, G3, H_N);
  gru_scan<<<NBLK, 256, 0, stream>>>(gxb, hx + B_N * H_N, whh1, bhh1, out,
                                     out + (size_t)T_N * B_N * H_N + B_N * H_N,
                                     hbuf, bar);
}

// Round 2
// 81980.957 us; speedup vs baseline: 1.2967x; 1.2967x over previous
//
#include <hip/hip_runtime.h>
#include <cstdint>
#include <cstddef>

#define T_N 1024
#define B_N 64
#define I_N 512
#define H_N 512
#define G3  (3*H_N)
#define NBLK 256   // scan blocks; one per CU, co-resident by construction
#define UPB  2     // hidden units per block (512/256)

// ---------------------------------------------------------------------------
// GEMM: C[m][n] = sum_k A[m][k]*W[n][k] + bias[n]   (A:[M,K], W:[N,K] row-major)
// ---------------------------------------------------------------------------
__global__ __launch_bounds__(256) void gemm_nt(
    const float* __restrict__ A,
    const float* __restrict__ W,
    const float* __restrict__ bias,
    float* __restrict__ C,
    int M, int N, int K)
{
  __shared__ float As[32][68];
  __shared__ float Ws[32][68];
  const int tid = threadIdx.x;
  const int n0 = blockIdx.x * 64;
  const int m0 = blockIdx.y * 64;
  const int ty = tid >> 4;   // 0..15
  const int tx = tid & 15;   // 0..15

  float acc[4][4];
#pragma unroll
  for (int i = 0; i < 4; ++i)
#pragma unroll
    for (int j = 0; j < 4; ++j) acc[i][j] = 0.f;

  for (int k0 = 0; k0 < K; k0 += 32) {
#pragma unroll
    for (int i = 0; i < 2; ++i) {
      int idx = tid + i * 256;     // 0..511
      int r   = idx >> 3;          // 0..63
      int c4  = idx & 7;           // 0..7
      float4 va = *(const float4*)(A + (size_t)(m0 + r) * K + k0 + c4 * 4);
      As[c4*4+0][r] = va.x; As[c4*4+1][r] = va.y;
      As[c4*4+2][r] = va.z; As[c4*4+3][r] = va.w;
      float4 vw = *(const float4*)(W + (size_t)(n0 + r) * K + k0 + c4 * 4);
      Ws[c4*4+0][r] = vw.x; Ws[c4*4+1][r] = vw.y;
      Ws[c4*4+2][r] = vw.z; Ws[c4*4+3][r] = vw.w;
    }
    __syncthreads();
#pragma unroll
    for (int k = 0; k < 32; ++k) {
      float4 a = *(const float4*)&As[k][ty * 4];
      float4 w = *(const float4*)&Ws[k][tx * 4];
      acc[0][0] += a.x*w.x; acc[0][1] += a.x*w.y; acc[0][2] += a.x*w.z; acc[0][3] += a.x*w.w;
      acc[1][0] += a.y*w.x; acc[1][1] += a.y*w.y; acc[1][2] += a.y*w.z; acc[1][3] += a.y*w.w;
      acc[2][0] += a.z*w.x; acc[2][1] += a.z*w.y; acc[2][2] += a.z*w.z; acc[2][3] += a.z*w.w;
      acc[3][0] += a.w*w.x; acc[3][1] += a.w*w.y; acc[3][2] += a.w*w.z; acc[3][3] += a.w*w.w;
    }
    __syncthreads();
  }

  float4 bv = *(const float4*)(bias + n0 + tx * 4);
#pragma unroll
  for (int i = 0; i < 4; ++i) {
    int row = m0 + ty * 4 + i;
    float4 o;
    o.x = acc[i][0] + bv.x; o.y = acc[i][1] + bv.y;
    o.z = acc[i][2] + bv.z; o.w = acc[i][3] + bv.w;
    *(float4*)(C + (size_t)row * N + n0 + tx * 4) = o;
  }
}

__device__ __forceinline__ float sigm_(float x) { return 1.f / (1.f + __expf(-x)); }

// ---------------------------------------------------------------------------
// Persistent GRU scan, one layer. Block b owns units j0=2b,2b+1 (w_hh rows in
// LDS, swizzled). Per step: all 256 threads compute partial dots reading h
// straight from global (L2/IF), LDS-reduce over 16 k-splits, gate on tid<64,
// then a contention-free padded-flag barrier (1 release-store per block,
// polling via 4 strided loads + __all).
// ---------------------------------------------------------------------------
__global__ __launch_bounds__(256) void gru_scan(
    const float* __restrict__ gx,     // [T][B][3H] (b_ih already added)
    const float* __restrict__ h0src,  // [B][H]
    const float* __restrict__ w_hh,   // [3H][H]
    const float* __restrict__ b_hh,   // [3H]
    float* __restrict__ out,          // [T][B][H]
    float* __restrict__ hT,           // [B][H]
    float* __restrict__ hbuf,         // 2*[B][H] double buffer
    int* __restrict__ flags)          // [NBLK][16] padded flags (zeroed)
{
  __shared__ float4 wl4[6 * 128];     // 12 KB, swizzled: [(k4&7)*16 + (k4>>3)]
  __shared__ float  red[6 * 64 * 20]; // 30 KB  k-split partials [g][b][s(20)]
  const int tid = threadIdx.x;
  const int bid = blockIdx.x;
  const int j0  = bid * UPB;

  // persistent weight load (once), bank-deconflict swizzle on k4
#pragma unroll
  for (int it = 0; it < 3; ++it) {
    int idx = it * 256 + tid;         // 0..767
    int g   = idx >> 7;               // 0..5  (= q*2+u)
    int k4  = idx & 127;
    int row = (g >> 1) * H_N + j0 + (g & 1);
    wl4[g * 128 + (k4 & 7) * 16 + (k4 >> 3)] =
        *(const float4*)(w_hh + (size_t)row * H_N + k4 * 4);
  }
  float2 br = {0,0}, bz = {0,0}, bn = {0,0};
  if (tid < 64) {
    br = *(const float2*)(b_hh + 0 * H_N + j0);
    bz = *(const float2*)(b_hh + 1 * H_N + j0);
    bn = *(const float2*)(b_hh + 2 * H_N + j0);
  }
  __syncthreads();

  const int bq = tid >> 4;   // 0..15 -> 4 batches each
  const int s  = tid & 15;   // k-split 0..15 (32 floats each)
  const int b0 = bq * 4;

  for (int t = 0; t < T_N; ++t) {
    const float* hsrc = (t == 0) ? h0src : (hbuf + (size_t)(t & 1) * B_N * H_N);
    float* hdst = hbuf + (size_t)((t + 1) & 1) * B_N * H_N;

    if (t > 0) {
      if (tid < 64) {
        for (;;) {
          int f0 = __hip_atomic_load(flags + (tid      ) * 16, __ATOMIC_ACQUIRE, __HIP_MEMORY_SCOPE_AGENT);
          int f1 = __hip_atomic_load(flags + (tid +  64) * 16, __ATOMIC_ACQUIRE, __HIP_MEMORY_SCOPE_AGENT);
          int f2 = __hip_atomic_load(flags + (tid + 128) * 16, __ATOMIC_ACQUIRE, __HIP_MEMORY_SCOPE_AGENT);
          int f3 = __hip_atomic_load(flags + (tid + 192) * 16, __ATOMIC_ACQUIRE, __HIP_MEMORY_SCOPE_AGENT);
          if (__all(f0 >= t && f1 >= t && f2 >= t && f3 >= t)) break;
          __builtin_amdgcn_s_sleep(2);
        }
        __threadfence();
      }
      __syncthreads();
    }

    // early-issue gate-phase inputs (overlap with compute below)
    float2 gr = {0,0}, gz = {0,0}, gn = {0,0}, hv = {0,0};
    if (tid < 64) {
      const size_t gxo = ((size_t)t * B_N + tid) * G3 + j0;
      gr = *(const float2*)(gx + gxo + 0 * H_N);
      gz = *(const float2*)(gx + gxo + 1 * H_N);
      gn = *(const float2*)(gx + gxo + 2 * H_N);
      hv = *(const float2*)(hsrc + (size_t)tid * H_N + j0);
    }

    float acc[6][4];
#pragma unroll
    for (int g = 0; g < 6; ++g)
#pragma unroll
      for (int bj = 0; bj < 4; ++bj) acc[g][bj] = 0.f;

#pragma unroll
    for (int i = 0; i < 8; ++i) {
      const int k4 = s * 8 + i;
      float4 h4[4];
#pragma unroll
      for (int bj = 0; bj < 4; ++bj)
        h4[bj] = *(const float4*)(hsrc + (size_t)(b0 + bj) * H_N + k4 * 4);
#pragma unroll
      for (int g = 0; g < 6; ++g) {
        float4 w4 = wl4[g * 128 + (k4 & 7) * 16 + (k4 >> 3)];
#pragma unroll
        for (int bj = 0; bj < 4; ++bj) {
          acc[g][bj] = fmaf(w4.x, h4[bj].x, acc[g][bj]);
          acc[g][bj] = fmaf(w4.y, h4[bj].y, acc[g][bj]);
          acc[g][bj] = fmaf(w4.z, h4[bj].z, acc[g][bj]);
          acc[g][bj] = fmaf(w4.w, h4[bj].w, acc[g][bj]);
        }
      }
    }

#pragma unroll
    for (int g = 0; g < 6; ++g)
#pragma unroll
      for (int bj = 0; bj < 4; ++bj)
        red[(g * 64 + b0 + bj) * 20 + s] = acc[g][bj];
    __syncthreads();

    if (tid < 64) {   // gate phase: thread = batch, both units
      float sg[6];
#pragma unroll
      for (int g = 0; g < 6; ++g) {
        const float* rp = &red[(g * 64 + tid) * 20];
        float4 a = *(const float4*)rp;
        float4 b4 = *(const float4*)(rp + 4);
        float4 c4 = *(const float4*)(rp + 8);
        float4 d4 = *(const float4*)(rp + 12);
        sg[g] = ((a.x + a.y) + (a.z + a.w)) + ((b4.x + b4.y) + (b4.z + b4.w))
              + ((c4.x + c4.y) + (c4.z + c4.w)) + ((d4.x + d4.y) + (d4.z + d4.w));
      }
      float hy[2];
#pragma unroll
      for (int u = 0; u < 2; ++u) {
        float ir = u ? gr.y : gr.x, iz = u ? gz.y : gz.x, in_ = u ? gn.y : gn.x;
        float hr = sg[0 + u] + (u ? br.y : br.x);
        float hz = sg[2 + u] + (u ? bz.y : bz.x);
        float hn = sg[4 + u] + (u ? bn.y : bn.x);
        float r = sigm_(ir + hr);
        float z = sigm_(iz + hz);
        float n = tanhf(in_ + r * hn);
        float h = u ? hv.y : hv.x;
        hy[u] = n + z * (h - n);
      }
      float2 o = {hy[0], hy[1]};
      *(float2*)(hdst + (size_t)tid * H_N + j0) = o;
      *(float2*)(out + ((size_t)t * B_N + tid) * H_N + j0) = o;
      if (t == T_N - 1) *(float2*)(hT + (size_t)tid * H_N + j0) = o;
      __threadfence();
    }
    __syncthreads();
    if (t + 1 < T_N && tid == 0)
      __hip_atomic_store(flags + bid * 16, t + 1, __ATOMIC_RELEASE, __HIP_MEMORY_SCOPE_AGENT);
  }
}

// ---------------------------------------------------------------------------
extern "C" void kernel_launch(void* const* d_in, const int* in_sizes, int n_in,
                              void* d_out, int out_size, void* d_ws, size_t ws_size,
                              hipStream_t stream)
{
  const float* x    = (const float*)d_in[0];
  const float* hx   = (const float*)d_in[1];
  const float* wih0 = (const float*)d_in[2];
  const float* whh0 = (const float*)d_in[3];
  const float* bih0 = (const float*)d_in[4];
  const float* bhh0 = (const float*)d_in[5];
  const float* wih1 = (const float*)d_in[6];
  const float* whh1 = (const float*)d_in[7];
  const float* bih1 = (const float*)d_in[8];
  const float* bhh1 = (const float*)d_in[9];
  float* out = (float*)d_out;   // [T*B*H] output, then [L*B*H] final hidden

  // workspace: gx [T*B*3H] | out0 [T*B*H] | hbuf 2*[B*H] | flags [NBLK*16]
  float* gxb  = (float*)d_ws;
  float* out0 = gxb + (size_t)T_N * B_N * G3;
  float* hbuf = out0 + (size_t)T_N * B_N * H_N;
  int*   flg  = (int*)(hbuf + 2 * B_N * H_N);

  dim3 gg(G3 / 64, (T_N * B_N) / 64);

  // layer 0
  hipMemsetAsync(flg, 0, NBLK * 16 * sizeof(int), stream);
  gemm_nt<<<gg, 256, 0, stream>>>(x, wih0, bih0, gxb, T_N * B_N, G3, I_N);
  gru_scan<<<NBLK, 256, 0, stream>>>(gxb, hx, whh0, bhh0, out0,
                                     out + (size_t)T_N * B_N * H_N, hbuf, flg);
  // layer 1
  hipMemsetAsync(flg, 0, NBLK * 16 * sizeof(int), stream);
  gemm_nt<<<gg, 256, 0, stream>>>(out0, wih1, bih1, gxb, T_N * B_N, G3, H_N);
  gru_scan<<<NBLK, 256, 0, stream>>>(gxb, hx + B_N * H_N, whh1, bhh1, out,
                                     out + (size_t)T_N * B_N * H_N + B_N * H_N,
                                     hbuf, flg);
}

// Round 3
// 39693.286 us; speedup vs baseline: 2.6781x; 2.0654x over previous
//
#include <hip/hip_runtime.h>
#include <cstdint>
#include <cstddef>

#define T_N 1024
#define B_N 64
#define I_N 512
#define H_N 512
#define G3  (3*H_N)
#define NBLK 256   // scan blocks; one per CU, co-resident by construction
#define UPB  2     // hidden units per block (512/256)

// ---------------------------------------------------------------------------
// GEMM: C[m][n] = sum_k A[m][k]*W[n][k] + bias[n]   (A:[M,K], W:[N,K] row-major)
// ---------------------------------------------------------------------------
__global__ __launch_bounds__(256) void gemm_nt(
    const float* __restrict__ A,
    const float* __restrict__ W,
    const float* __restrict__ bias,
    float* __restrict__ C,
    int M, int N, int K)
{
  __shared__ float As[32][68];
  __shared__ float Ws[32][68];
  const int tid = threadIdx.x;
  const int n0 = blockIdx.x * 64;
  const int m0 = blockIdx.y * 64;
  const int ty = tid >> 4;   // 0..15
  const int tx = tid & 15;   // 0..15

  float acc[4][4];
#pragma unroll
  for (int i = 0; i < 4; ++i)
#pragma unroll
    for (int j = 0; j < 4; ++j) acc[i][j] = 0.f;

  for (int k0 = 0; k0 < K; k0 += 32) {
#pragma unroll
    for (int i = 0; i < 2; ++i) {
      int idx = tid + i * 256;     // 0..511
      int r   = idx >> 3;          // 0..63
      int c4  = idx & 7;           // 0..7
      float4 va = *(const float4*)(A + (size_t)(m0 + r) * K + k0 + c4 * 4);
      As[c4*4+0][r] = va.x; As[c4*4+1][r] = va.y;
      As[c4*4+2][r] = va.z; As[c4*4+3][r] = va.w;
      float4 vw = *(const float4*)(W + (size_t)(n0 + r) * K + k0 + c4 * 4);
      Ws[c4*4+0][r] = vw.x; Ws[c4*4+1][r] = vw.y;
      Ws[c4*4+2][r] = vw.z; Ws[c4*4+3][r] = vw.w;
    }
    __syncthreads();
#pragma unroll
    for (int k = 0; k < 32; ++k) {
      float4 a = *(const float4*)&As[k][ty * 4];
      float4 w = *(const float4*)&Ws[k][tx * 4];
      acc[0][0] += a.x*w.x; acc[0][1] += a.x*w.y; acc[0][2] += a.x*w.z; acc[0][3] += a.x*w.w;
      acc[1][0] += a.y*w.x; acc[1][1] += a.y*w.y; acc[1][2] += a.y*w.z; acc[1][3] += a.y*w.w;
      acc[2][0] += a.z*w.x; acc[2][1] += a.z*w.y; acc[2][2] += a.z*w.z; acc[2][3] += a.z*w.w;
      acc[3][0] += a.w*w.x; acc[3][1] += a.w*w.y; acc[3][2] += a.w*w.z; acc[3][3] += a.w*w.w;
    }
    __syncthreads();
  }

  float4 bv = *(const float4*)(bias + n0 + tx * 4);
#pragma unroll
  for (int i = 0; i < 4; ++i) {
    int row = m0 + ty * 4 + i;
    float4 o;
    o.x = acc[i][0] + bv.x; o.y = acc[i][1] + bv.y;
    o.z = acc[i][2] + bv.z; o.w = acc[i][3] + bv.w;
    *(float4*)(C + (size_t)row * N + n0 + tx * 4) = o;
  }
}

__device__ __forceinline__ float sigm_(float x) { return 1.f / (1.f + __expf(-x)); }

// ---------------------------------------------------------------------------
// Persistent GRU scan, one layer. Block b owns units j0=2b,2b+1 (w_hh rows in
// LDS, swizzled). Per step: 256 threads compute partial dots reading h from
// global (L2/IF), LDS-reduce over 16 k-splits, gate on tid<64 (h kept in
// registers), then a fence-minimal flag barrier: RELAXED polls (no cache
// invalidates), exactly one acquire fence on exit / one release fence on
// arrival.
// ---------------------------------------------------------------------------
__global__ __launch_bounds__(256) void gru_scan(
    const float* __restrict__ gx,     // [T][B][3H] (b_ih already added)
    const float* __restrict__ h0src,  // [B][H]
    const float* __restrict__ w_hh,   // [3H][H]
    const float* __restrict__ b_hh,   // [3H]
    float* __restrict__ out,          // [T][B][H]
    float* __restrict__ hT,           // [B][H]
    float* __restrict__ hbuf,         // 2*[B][H] double buffer
    int* __restrict__ flags)          // [NBLK][16] padded flags (zeroed)
{
  __shared__ float4 wl4[6 * 128];     // 12 KB, swizzled: [(k4&7)*16 + (k4>>3)]
  __shared__ float  red[6 * 64 * 20]; // 30 KB  k-split partials [g][b][s(20)]
  const int tid = threadIdx.x;
  const int bid = blockIdx.x;
  const int j0  = bid * UPB;

  // persistent weight load (once), bank-deconflict swizzle on k4
#pragma unroll
  for (int it = 0; it < 3; ++it) {
    int idx = it * 256 + tid;         // 0..767
    int g   = idx >> 7;               // 0..5  (= q*2+u)
    int k4  = idx & 127;
    int row = (g >> 1) * H_N + j0 + (g & 1);
    wl4[g * 128 + (k4 & 7) * 16 + (k4 >> 3)] =
        *(const float4*)(w_hh + (size_t)row * H_N + k4 * 4);
  }
  float2 br = {0,0}, bz = {0,0}, bn = {0,0};
  float2 hv = {0,0};
  if (tid < 64) {
    br = *(const float2*)(b_hh + 0 * H_N + j0);
    bz = *(const float2*)(b_hh + 1 * H_N + j0);
    bn = *(const float2*)(b_hh + 2 * H_N + j0);
    hv = *(const float2*)(h0src + (size_t)tid * H_N + j0);   // h_{-1} for my batch/units
  }
  __syncthreads();

  const int bq = tid >> 4;   // 0..15 -> 4 batches each
  const int s  = tid & 15;   // k-split 0..15 (32 floats each)
  const int b0 = bq * 4;

  for (int t = 0; t < T_N; ++t) {
    const float* hsrc = (t == 0) ? h0src : (hbuf + (size_t)(t & 1) * B_N * H_N);
    float* hdst = hbuf + (size_t)((t + 1) & 1) * B_N * H_N;

    // gate-phase gx inputs: independent of the barrier -> issue before poll
    float2 gr = {0,0}, gz = {0,0}, gn = {0,0};
    if (tid < 64) {
      const size_t gxo = ((size_t)t * B_N + tid) * G3 + j0;
      gr = *(const float2*)(gx + gxo + 0 * H_N);
      gz = *(const float2*)(gx + gxo + 1 * H_N);
      gn = *(const float2*)(gx + gxo + 2 * H_N);
    }

    if (t > 0) {
      if (tid < 64) {
        int spin = 0;
        for (;;) {
          int f0 = __hip_atomic_load(flags + (tid      ) * 16, __ATOMIC_RELAXED, __HIP_MEMORY_SCOPE_AGENT);
          int f1 = __hip_atomic_load(flags + (tid +  64) * 16, __ATOMIC_RELAXED, __HIP_MEMORY_SCOPE_AGENT);
          int f2 = __hip_atomic_load(flags + (tid + 128) * 16, __ATOMIC_RELAXED, __HIP_MEMORY_SCOPE_AGENT);
          int f3 = __hip_atomic_load(flags + (tid + 192) * 16, __ATOMIC_RELAXED, __HIP_MEMORY_SCOPE_AGENT);
          if (__all(f0 >= t && f1 >= t && f2 >= t && f3 >= t)) break;
          __builtin_amdgcn_s_sleep(2);
          if ((++spin & 63) == 0)   // safety valve: periodic real acquire
            __builtin_amdgcn_fence(__ATOMIC_ACQUIRE, "agent");
        }
        // one invalidate per step: makes remote h stores visible to plain loads
        __builtin_amdgcn_fence(__ATOMIC_ACQUIRE, "agent");
      }
      __syncthreads();
    }

    float acc[6][4];
#pragma unroll
    for (int g = 0; g < 6; ++g)
#pragma unroll
      for (int bj = 0; bj < 4; ++bj) acc[g][bj] = 0.f;

#pragma unroll
    for (int i = 0; i < 8; ++i) {
      const int k4 = s * 8 + i;
      float4 h4[4];
#pragma unroll
      for (int bj = 0; bj < 4; ++bj)
        h4[bj] = *(const float4*)(hsrc + (size_t)(b0 + bj) * H_N + k4 * 4);
#pragma unroll
      for (int g = 0; g < 6; ++g) {
        float4 w4 = wl4[g * 128 + (k4 & 7) * 16 + (k4 >> 3)];
#pragma unroll
        for (int bj = 0; bj < 4; ++bj) {
          acc[g][bj] = fmaf(w4.x, h4[bj].x, acc[g][bj]);
          acc[g][bj] = fmaf(w4.y, h4[bj].y, acc[g][bj]);
          acc[g][bj] = fmaf(w4.z, h4[bj].z, acc[g][bj]);
          acc[g][bj] = fmaf(w4.w, h4[bj].w, acc[g][bj]);
        }
      }
    }

#pragma unroll
    for (int g = 0; g < 6; ++g)
#pragma unroll
      for (int bj = 0; bj < 4; ++bj)
        red[(g * 64 + b0 + bj) * 20 + s] = acc[g][bj];
    __syncthreads();

    if (tid < 64) {   // gate phase: thread = batch, both units
      float sg[6];
#pragma unroll
      for (int g = 0; g < 6; ++g) {
        const float* rp = &red[(g * 64 + tid) * 20];
        float4 a = *(const float4*)rp;
        float4 b4 = *(const float4*)(rp + 4);
        float4 c4 = *(const float4*)(rp + 8);
        float4 d4 = *(const float4*)(rp + 12);
        sg[g] = ((a.x + a.y) + (a.z + a.w)) + ((b4.x + b4.y) + (b4.z + b4.w))
              + ((c4.x + c4.y) + (c4.z + c4.w)) + ((d4.x + d4.y) + (d4.z + d4.w));
      }
      float hy[2];
#pragma unroll
      for (int u = 0; u < 2; ++u) {
        float ir = u ? gr.y : gr.x, iz = u ? gz.y : gz.x, in_ = u ? gn.y : gn.x;
        float hr = sg[0 + u] + (u ? br.y : br.x);
        float hz = sg[2 + u] + (u ? bz.y : bz.x);
        float hn = sg[4 + u] + (u ? bn.y : bn.x);
        float r = sigm_(ir + hr);
        float z = sigm_(iz + hz);
        float n = tanhf(in_ + r * hn);
        float h = u ? hv.y : hv.x;
        hy[u] = n + z * (h - n);
      }
      float2 o = {hy[0], hy[1]};
      hv = o;   // keep my own h in registers for next step's gate phase
      *(float2*)(hdst + (size_t)tid * H_N + j0) = o;
      *(float2*)(out + ((size_t)t * B_N + tid) * H_N + j0) = o;
      if (t == T_N - 1) *(float2*)(hT + (size_t)tid * H_N + j0) = o;
      if (t + 1 < T_N) {
        // one release fence (L2 writeback), then an uncontended relaxed flag
        __builtin_amdgcn_fence(__ATOMIC_RELEASE, "agent");
        if (tid == 0)
          __hip_atomic_store(flags + bid * 16, t + 1, __ATOMIC_RELAXED, __HIP_MEMORY_SCOPE_AGENT);
      }
    }
  }
}

// ---------------------------------------------------------------------------
extern "C" void kernel_launch(void* const* d_in, const int* in_sizes, int n_in,
                              void* d_out, int out_size, void* d_ws, size_t ws_size,
                              hipStream_t stream)
{
  const float* x    = (const float*)d_in[0];
  const float* hx   = (const float*)d_in[1];
  const float* wih0 = (const float*)d_in[2];
  const float* whh0 = (const float*)d_in[3];
  const float* bih0 = (const float*)d_in[4];
  const float* bhh0 = (const float*)d_in[5];
  const float* wih1 = (const float*)d_in[6];
  const float* whh1 = (const float*)d_in[7];
  const float* bih1 = (const float*)d_in[8];
  const float* bhh1 = (const float*)d_in[9];
  float* out = (float*)d_out;   // [T*B*H] output, then [L*B*H] final hidden

  // workspace: gx [T*B*3H] | out0 [T*B*H] | hbuf 2*[B*H] | flags [NBLK*16]
  float* gxb  = (float*)d_ws;
  float* out0 = gxb + (size_t)T_N * B_N * G3;
  float* hbuf = out0 + (size_t)T_N * B_N * H_N;
  int*   flg  = (int*)(hbuf + 2 * B_N * H_N);

  dim3 gg(G3 / 64, (T_N * B_N) / 64);

  // layer 0
  hipMemsetAsync(flg, 0, NBLK * 16 * sizeof(int), stream);
  gemm_nt<<<gg, 256, 0, stream>>>(x, wih0, bih0, gxb, T_N * B_N, G3, I_N);
  gru_scan<<<NBLK, 256, 0, stream>>>(gxb, hx, whh0, bhh0, out0,
                                     out + (size_t)T_N * B_N * H_N, hbuf, flg);
  // layer 1
  hipMemsetAsync(flg, 0, NBLK * 16 * sizeof(int), stream);
  gemm_nt<<<gg, 256, 0, stream>>>(out0, wih1, bih1, gxb, T_N * B_N, G3, H_N);
  gru_scan<<<NBLK, 256, 0, stream>>>(gxb, hx + B_N * H_N, whh1, bhh1, out,
                                     out + (size_t)T_N * B_N * H_N + B_N * H_N,
                                     hbuf, flg);
}

// Round 4
// 18978.201 us; speedup vs baseline: 5.6013x; 2.0915x over previous
//
#include <hip/hip_runtime.h>
#include <cstdint>
#include <cstddef>

#define T_N 1024
#define B_N 64
#define I_N 512
#define H_N 512
#define G3  (3*H_N)
#define NGRP 8            // batch groups (8 batches each)
#define GBLK 32           // blocks per group
#define NBLK (NGRP*GBLK)  // 256 blocks total
#define UPB  16           // units per block

// rotated h layout: f4-index permutation within a 128-f4 row so that the
// compute-phase LDS reads are lane-consecutive (conflict-free).
__device__ __forceinline__ int rot4(int k4) { return ((k4 & 3) << 5) | (k4 >> 2); }
__device__ __forceinline__ int rpos(int k)  { return rot4(k >> 2) * 4 + (k & 3); }

// ---------------------------------------------------------------------------
// GEMM: C[m][n] = sum_k A[m][k]*W[n][k] + bias[n]
// ---------------------------------------------------------------------------
__global__ __launch_bounds__(256) void gemm_nt(
    const float* __restrict__ A,
    const float* __restrict__ W,
    const float* __restrict__ bias,
    float* __restrict__ C,
    int M, int N, int K)
{
  __shared__ float As[32][68];
  __shared__ float Ws[32][68];
  const int tid = threadIdx.x;
  const int n0 = blockIdx.x * 64;
  const int m0 = blockIdx.y * 64;
  const int ty = tid >> 4;
  const int tx = tid & 15;

  float acc[4][4];
#pragma unroll
  for (int i = 0; i < 4; ++i)
#pragma unroll
    for (int j = 0; j < 4; ++j) acc[i][j] = 0.f;

  for (int k0 = 0; k0 < K; k0 += 32) {
#pragma unroll
    for (int i = 0; i < 2; ++i) {
      int idx = tid + i * 256;
      int r   = idx >> 3;
      int c4  = idx & 7;
      float4 va = *(const float4*)(A + (size_t)(m0 + r) * K + k0 + c4 * 4);
      As[c4*4+0][r] = va.x; As[c4*4+1][r] = va.y;
      As[c4*4+2][r] = va.z; As[c4*4+3][r] = va.w;
      float4 vw = *(const float4*)(W + (size_t)(n0 + r) * K + k0 + c4 * 4);
      Ws[c4*4+0][r] = vw.x; Ws[c4*4+1][r] = vw.y;
      Ws[c4*4+2][r] = vw.z; Ws[c4*4+3][r] = vw.w;
    }
    __syncthreads();
#pragma unroll
    for (int k = 0; k < 32; ++k) {
      float4 a = *(const float4*)&As[k][ty * 4];
      float4 w = *(const float4*)&Ws[k][tx * 4];
      acc[0][0] += a.x*w.x; acc[0][1] += a.x*w.y; acc[0][2] += a.x*w.z; acc[0][3] += a.x*w.w;
      acc[1][0] += a.y*w.x; acc[1][1] += a.y*w.y; acc[1][2] += a.y*w.z; acc[1][3] += a.y*w.w;
      acc[2][0] += a.z*w.x; acc[2][1] += a.z*w.y; acc[2][2] += a.z*w.z; acc[2][3] += a.z*w.w;
      acc[3][0] += a.w*w.x; acc[3][1] += a.w*w.y; acc[3][2] += a.w*w.z; acc[3][3] += a.w*w.w;
    }
    __syncthreads();
  }

  float4 bv = *(const float4*)(bias + n0 + tx * 4);
#pragma unroll
  for (int i = 0; i < 4; ++i) {
    int row = m0 + ty * 4 + i;
    float4 o;
    o.x = acc[i][0] + bv.x; o.y = acc[i][1] + bv.y;
    o.z = acc[i][2] + bv.z; o.w = acc[i][3] + bv.w;
    *(float4*)(C + (size_t)row * N + n0 + tx * 4) = o;
  }
}

// pre-rotate h0 into hbufR buffer 0
__global__ __launch_bounds__(256) void rot_h0(
    const float* __restrict__ src, float* __restrict__ dst)
{
  int idx = blockIdx.x * 256 + threadIdx.x;   // 0..32767
  int b = idx >> 9, k = idx & 511;
  dst[b * 512 + rpos(k)] = src[idx];
}

__device__ __forceinline__ float sigm_(float x) { return 1.f / (1.f + __expf(-x)); }

// ---------------------------------------------------------------------------
// Group-local persistent GRU scan. Group g (blocks with blockIdx%8==g) owns
// batches 8g..8g+7; block j-in-group owns units 16j..16j+15. w_hh slice lives
// in REGISTERS for all 1024 steps. h is exchanged through IF via relaxed
// agent-scope atomics (cache-bypassing, NO fences anywhere), staged in LDS.
// ---------------------------------------------------------------------------
__global__ __launch_bounds__(256, 1) void gru_scan(
    const float* __restrict__ gx,     // [T][64][1536] (b_ih added)
    const float* __restrict__ h0,     // [64][512] normal layout
    const float* __restrict__ w_hh,   // [1536][512]
    const float* __restrict__ b_hh,   // [1536]
    float* __restrict__ out,          // [T][64][512]
    float* __restrict__ hT,           // [64][512]
    float* __restrict__ hbufR,        // 2 x [64][512] ROTATED layout
    int* __restrict__ flags)          // [256][16], zeroed
{
  __shared__ float hl[8 * 512];        // 16 KB staged rotated h (linear copy)
  __shared__ float red[384 * 36];      // 54 KB k-split partials, stride 36

  const int tid = threadIdx.x;
  const int g   = blockIdx.x & 7;      // batch group
  const int j   = blockIdx.x >> 3;     // block in group (0..31)
  const int up  = tid >> 5;            // unit-pair 0..7
  const int s   = tid & 31;            // k-split 0..31 (16 floats each)

  // ---- persistent weight slice in registers: 3 gates x 2 units x 16 k ----
  float4 wr[3][2][4];
#pragma unroll
  for (int q = 0; q < 3; ++q)
#pragma unroll
    for (int e = 0; e < 2; ++e) {
      const float* wp = w_hh + (size_t)(q * H_N + 16 * j + 2 * up + e) * H_N + s * 16;
#pragma unroll
      for (int c = 0; c < 4; ++c) wr[q][e][c] = *(const float4*)(wp + c * 4);
    }

  // gate-phase thread identity: u = tid&15 (unit), b = tid>>4 (batch in group)
  const int gu = tid & 15;
  const int gb8 = tid >> 4;            // 0..7 valid when tid<128
  float bR = 0, bZ = 0, bN = 0, hv = 0;
  if (tid < 128) {
    int unit = 16 * j + gu;
    bR = b_hh[0 * H_N + unit];
    bZ = b_hh[1 * H_N + unit];
    bN = b_hh[2 * H_N + unit];
    hv = h0[(size_t)(8 * g + gb8) * H_N + unit];
  }

  for (int t = 0; t < T_N; ++t) {
    // gx inputs for the gate phase: plain cached loads, issued before poll
    float ir = 0, iz = 0, inn = 0;
    if (tid < 128) {
      const float* p = gx + ((size_t)t * B_N + 8 * g + gb8) * G3 + 16 * j + gu;
      ir  = p[0];
      iz  = p[H_N];
      inn = p[2 * H_N];
    }

    if (t > 0) {
      if (tid < 64) {
        int spin = 0;
        for (;;) {
          int f = __hip_atomic_load(flags + (8 * (tid & 31) + g) * 16,
                                    __ATOMIC_RELAXED, __HIP_MEMORY_SCOPE_AGENT);
          if (__all(f >= t)) break;
          __builtin_amdgcn_s_sleep(1);
          if ((++spin & 4095) == 0)   // hang-guard only; ~never fires
            __builtin_amdgcn_fence(__ATOMIC_ACQUIRE, "agent");
        }
      }
      __syncthreads();
    }

    // ---- stage this group's h (rotated layout -> linear LDS copy) ----
    {
      const float* hsrc = hbufR + (size_t)(t & 1) * (B_N * H_N) + (size_t)(8 * g) * H_N;
#pragma unroll
      for (int e = 0; e < 16; ++e)
        hl[e * 256 + tid] = __hip_atomic_load((float*)(hsrc + e * 256 + tid),
                                              __ATOMIC_RELAXED, __HIP_MEMORY_SCOPE_AGENT);
    }
    __syncthreads();

    // ---- compute: 3 gates x 2 units x 8 batches, k in [16s,16s+16) ----
    float acc[3][2][8];
#pragma unroll
    for (int q = 0; q < 3; ++q)
#pragma unroll
      for (int e = 0; e < 2; ++e)
#pragma unroll
        for (int bb = 0; bb < 8; ++bb) acc[q][e][bb] = 0.f;

#pragma unroll
    for (int i = 0; i < 4; ++i) {
      float4 h4[8];
#pragma unroll
      for (int bb = 0; bb < 8; ++bb)
        h4[bb] = *(const float4*)&hl[(bb * 128 + i * 32 + s) * 4];
#pragma unroll
      for (int q = 0; q < 3; ++q)
#pragma unroll
        for (int e = 0; e < 2; ++e) {
          float4 w4 = wr[q][e][i];
#pragma unroll
          for (int bb = 0; bb < 8; ++bb) {
            acc[q][e][bb] = fmaf(w4.x, h4[bb].x, acc[q][e][bb]);
            acc[q][e][bb] = fmaf(w4.y, h4[bb].y, acc[q][e][bb]);
            acc[q][e][bb] = fmaf(w4.z, h4[bb].z, acc[q][e][bb]);
            acc[q][e][bb] = fmaf(w4.w, h4[bb].w, acc[q][e][bb]);
          }
        }
    }

    // ---- k-split reduction partials to LDS (lane-consecutive: no conflicts)
#pragma unroll
    for (int q = 0; q < 3; ++q)
#pragma unroll
      for (int e = 0; e < 2; ++e)
#pragma unroll
        for (int bb = 0; bb < 8; ++bb)
          red[((2 * up + e) + 16 * (q * 8 + bb)) * 36 + s] = acc[q][e][bb];
    __syncthreads();

    // ---- gate phase on tid<128: (unit gu, batch gb8) ----
    if (tid < 128) {
      float sg[3];
#pragma unroll
      for (int q = 0; q < 3; ++q) {
        const float* rp = &red[(gu + 16 * (q * 8 + gb8)) * 36];
        float4 a = *(const float4*)(rp + 0);
        float4 b4 = *(const float4*)(rp + 4);
        float4 c4 = *(const float4*)(rp + 8);
        float4 d4 = *(const float4*)(rp + 12);
        float4 a2 = *(const float4*)(rp + 16);
        float4 b2 = *(const float4*)(rp + 20);
        float4 c2 = *(const float4*)(rp + 24);
        float4 d2 = *(const float4*)(rp + 28);
        sg[q] = (((a.x + a.y) + (a.z + a.w)) + ((b4.x + b4.y) + (b4.z + b4.w)))
              + (((c4.x + c4.y) + (c4.z + c4.w)) + ((d4.x + d4.y) + (d4.z + d4.w)))
              + (((a2.x + a2.y) + (a2.z + a2.w)) + ((b2.x + b2.y) + (b2.z + b2.w)))
              + (((c2.x + c2.y) + (c2.z + c2.w)) + ((d2.x + d2.y) + (d2.z + d2.w)));
      }
      float r = sigm_(ir + sg[0] + bR);
      float z = sigm_(iz + sg[1] + bZ);
      float n = tanhf(inn + r * (sg[2] + bN));
      float hy = n + z * (hv - n);
      hv = hy;

      const int unit = 16 * j + gu;
      const int gbi  = 8 * g + gb8;
      out[((size_t)t * B_N + gbi) * H_N + unit] = hy;          // plain store
      if (t == T_N - 1) hT[(size_t)gbi * H_N + unit] = hy;     // plain store
      // rotated-layout coherent store for the exchange
      float* hd = hbufR + (size_t)((t + 1) & 1) * (B_N * H_N);
      int pos = (gu >> 2) * 128 + j * 4 + (gu & 3);
      __hip_atomic_store(hd + (size_t)gbi * H_N + pos, hy,
                         __ATOMIC_RELAXED, __HIP_MEMORY_SCOPE_AGENT);
    }
    asm volatile("s_waitcnt vmcnt(0)" ::: "memory");
    __syncthreads();
    if (t + 1 < T_N && tid == 0)
      __hip_atomic_store(flags + blockIdx.x * 16, t + 1,
                         __ATOMIC_RELAXED, __HIP_MEMORY_SCOPE_AGENT);
  }
}

// ---------------------------------------------------------------------------
extern "C" void kernel_launch(void* const* d_in, const int* in_sizes, int n_in,
                              void* d_out, int out_size, void* d_ws, size_t ws_size,
                              hipStream_t stream)
{
  const float* x    = (const float*)d_in[0];
  const float* hx   = (const float*)d_in[1];
  const float* wih0 = (const float*)d_in[2];
  const float* whh0 = (const float*)d_in[3];
  const float* bih0 = (const float*)d_in[4];
  const float* bhh0 = (const float*)d_in[5];
  const float* wih1 = (const float*)d_in[6];
  const float* whh1 = (const float*)d_in[7];
  const float* bih1 = (const float*)d_in[8];
  const float* bhh1 = (const float*)d_in[9];
  float* out = (float*)d_out;   // [T*B*H] output, then [L*B*H] final hidden

  // workspace: gx [T*B*3H] | out0 [T*B*H] | hbufR 2*[B*H] | flags [256*16]
  float* gxb  = (float*)d_ws;
  float* out0 = gxb + (size_t)T_N * B_N * G3;
  float* hbr  = out0 + (size_t)T_N * B_N * H_N;
  int*   flg  = (int*)(hbr + 2 * B_N * H_N);

  dim3 gg(G3 / 64, (T_N * B_N) / 64);

  // layer 0
  hipMemsetAsync(flg, 0, NBLK * 16 * sizeof(int), stream);
  gemm_nt<<<gg, 256, 0, stream>>>(x, wih0, bih0, gxb, T_N * B_N, G3, I_N);
  rot_h0<<<128, 256, 0, stream>>>(hx, hbr);
  gru_scan<<<NBLK, 256, 0, stream>>>(gxb, hx, whh0, bhh0, out0,
                                     out + (size_t)T_N * B_N * H_N, hbr, flg);
  // layer 1
  hipMemsetAsync(flg, 0, NBLK * 16 * sizeof(int), stream);
  gemm_nt<<<gg, 256, 0, stream>>>(out0, wih1, bih1, gxb, T_N * B_N, G3, H_N);
  rot_h0<<<128, 256, 0, stream>>>(hx + B_N * H_N, hbr);
  gru_scan<<<NBLK, 256, 0, stream>>>(gxb, hx + B_N * H_N, whh1, bhh1, out,
                                     out + (size_t)T_N * B_N * H_N + B_N * H_N,
                                     hbr, flg);
}

// Round 5
// 10333.064 us; speedup vs baseline: 10.2876x; 1.8366x over previous
//
#include <hip/hip_runtime.h>
#include <cstdint>
#include <cstddef>

#define T_N 1024
#define B_N 64
#define I_N 512
#define H_N 512
#define G3  (3*H_N)
#define NBLK 256   // 8 groups (8 batches) x 32 blocks (16 units each)

typedef _Float16 f16;
typedef _Float16 f16x2 __attribute__((ext_vector_type(2)));

__device__ __forceinline__ f16x2 mkh2(float a, float b) {
  f16x2 v; v.x = (_Float16)a; v.y = (_Float16)b; return v;
}
__device__ __forceinline__ f16x2 bch2(unsigned int u) {
  return __builtin_bit_cast(f16x2, u);
}
__device__ __forceinline__ float fdot2_(f16x2 a, f16x2 b, float c) {
#if __has_builtin(__builtin_amdgcn_fdot2)
  return __builtin_amdgcn_fdot2(a, b, c, false);
#else
  return fmaf((float)a.x, (float)b.x, fmaf((float)a.y, (float)b.y, c));
#endif
}
__device__ __forceinline__ float sigm_(float x) { return 1.f / (1.f + __expf(-x)); }

// ---------------------------------------------------------------------------
// GEMM: C[m][n] = sum_k A[m][k]*W[n][k] + bias[n]   (layer-0 input gates only)
// ---------------------------------------------------------------------------
__global__ __launch_bounds__(256) void gemm_nt(
    const float* __restrict__ A,
    const float* __restrict__ W,
    const float* __restrict__ bias,
    float* __restrict__ C,
    int M, int N, int K)
{
  __shared__ float As[32][68];
  __shared__ float Ws[32][68];
  const int tid = threadIdx.x;
  const int n0 = blockIdx.x * 64;
  const int m0 = blockIdx.y * 64;
  const int ty = tid >> 4;
  const int tx = tid & 15;

  float acc[4][4];
#pragma unroll
  for (int i = 0; i < 4; ++i)
#pragma unroll
    for (int j = 0; j < 4; ++j) acc[i][j] = 0.f;

  for (int k0 = 0; k0 < K; k0 += 32) {
#pragma unroll
    for (int i = 0; i < 2; ++i) {
      int idx = tid + i * 256;
      int r   = idx >> 3;
      int c4  = idx & 7;
      float4 va = *(const float4*)(A + (size_t)(m0 + r) * K + k0 + c4 * 4);
      As[c4*4+0][r] = va.x; As[c4*4+1][r] = va.y;
      As[c4*4+2][r] = va.z; As[c4*4+3][r] = va.w;
      float4 vw = *(const float4*)(W + (size_t)(n0 + r) * K + k0 + c4 * 4);
      Ws[c4*4+0][r] = vw.x; Ws[c4*4+1][r] = vw.y;
      Ws[c4*4+2][r] = vw.z; Ws[c4*4+3][r] = vw.w;
    }
    __syncthreads();
#pragma unroll
    for (int k = 0; k < 32; ++k) {
      float4 a = *(const float4*)&As[k][ty * 4];
      float4 w = *(const float4*)&Ws[k][tx * 4];
      acc[0][0] += a.x*w.x; acc[0][1] += a.x*w.y; acc[0][2] += a.x*w.z; acc[0][3] += a.x*w.w;
      acc[1][0] += a.y*w.x; acc[1][1] += a.y*w.y; acc[1][2] += a.y*w.z; acc[1][3] += a.y*w.w;
      acc[2][0] += a.z*w.x; acc[2][1] += a.z*w.y; acc[2][2] += a.z*w.z; acc[2][3] += a.z*w.w;
      acc[3][0] += a.w*w.x; acc[3][1] += a.w*w.y; acc[3][2] += a.w*w.z; acc[3][3] += a.w*w.w;
    }
    __syncthreads();
  }

  float4 bv = *(const float4*)(bias + n0 + tx * 4);
#pragma unroll
  for (int i = 0; i < 4; ++i) {
    int row = m0 + ty * 4 + i;
    float4 o;
    o.x = acc[i][0] + bv.x; o.y = acc[i][1] + bv.y;
    o.z = acc[i][2] + bv.z; o.w = acc[i][3] + bv.w;
    *(float4*)(C + (size_t)row * N + n0 + tx * 4) = o;
  }
}

// pack fp32 initial hidden states to fp16 exchange slot 1
__global__ __launch_bounds__(256) void pack_h_init(
    const float* __restrict__ hx, f16* h0x1, f16* h1x1)
{
  int i = blockIdx.x * 256 + threadIdx.x;   // 0..32767
  h0x1[i] = (f16)hx[i];
  h1x1[i] = (f16)hx[B_N * H_N + i];
}

// ---------------------------------------------------------------------------
// Fused 2-layer pipelined persistent scan.
// Step t (0..1024): phase A computes h0_t (uses staged h0_{t-1}); phase B
// computes h1_{t-1} (uses the SAME staged h0_{t-1} as x-input + h1_{t-2}).
// Group g = bid&7 owns batches 8g..8g+7; block j = bid>>3 owns units 16j..+15.
// fp16 weights in registers (dot2, fp32 accum); fp16 h exchange via relaxed
// agent-scope atomics (IF-coherent, fence-free); fp32 gate math.
// ---------------------------------------------------------------------------
__global__ __launch_bounds__(256, 1) void gru_fused(
    const float* __restrict__ gx,    // [T][64][1536] layer-0 input gates
    const float* __restrict__ hx,    // [2][64][512] fp32 initial h
    const float* wih1, const float* whh0, const float* whh1,   // no restrict
    const float* bih1, const float* bhh0, const float* bhh1,
    float* __restrict__ out,         // [T][64][512]
    float* __restrict__ hT,          // [2][64][512]
    f16* h0x, f16* h1x,              // 2 x [64][512] fp16 exchange rings
    int* flags0, int* flags1)        // [256][16] each, zeroed
{
  __shared__ f16 sh0[8 * 512];            // 8 KB staged h0_{t-1} (this group)
  __shared__ f16 sh1[8 * 512];            // 8 KB staged h1_{t-2}
  __shared__ float red[512 * 36];         // 72 KB k-split partials
  __shared__ __align__(8) unsigned short pk[128];  // gate->exchange packer

  const int tid = threadIdx.x;
  const int bid = blockIdx.x;
  const int g   = bid & 7;
  const int j   = bid >> 3;
  const int up  = tid >> 5;   // unit pair 0..7
  const int s   = tid & 31;   // k split 0..31

  // ---- persistent fp16 weights in registers ----
  // thread's k-set: halfs [8s,8s+8) U [8s+256,8s+264)  (chunk s and s+32)
  f16x2 wA[3][2][8];   // layer0 w_hh
  f16x2 wX[3][2][8];   // layer1 w_ih
  f16x2 wH[3][2][8];   // layer1 w_hh
#pragma unroll
  for (int q = 0; q < 3; ++q)
#pragma unroll
    for (int e = 0; e < 2; ++e) {
      const size_t row = (size_t)(q * H_N + 16 * j + 2 * up + e);
      const float* pA = whh0 + row * H_N;
      const float* pX = wih1 + row * H_N;
      const float* pH = whh1 + row * H_N;
#pragma unroll
      for (int c = 0; c < 4; ++c) {
        const int k0 = 8 * s + 2 * c;
        const int k1 = 256 + 8 * s + 2 * c;
        wA[q][e][c]     = mkh2(pA[k0], pA[k0 + 1]);
        wA[q][e][4 + c] = mkh2(pA[k1], pA[k1 + 1]);
        wX[q][e][c]     = mkh2(pX[k0], pX[k0 + 1]);
        wX[q][e][4 + c] = mkh2(pX[k1], pX[k1 + 1]);
        wH[q][e][c]     = mkh2(pH[k0], pH[k0 + 1]);
        wH[q][e][4 + c] = mkh2(pH[k1], pH[k1 + 1]);
      }
    }

  // gate-phase identity (tid<128): unit gu, batch-in-group gb8
  const int gu = tid & 15;
  const int gb8 = tid >> 4;
  float bR0=0,bZ0=0,bN0=0, xR1=0,xZ1=0,xN1=0, hR1=0,hZ1=0,hN1=0, hv0=0, hv1=0;
  if (tid < 128) {
    const int unit = 16 * j + gu;
    const int gbi  = 8 * g + gb8;
    bR0 = bhh0[unit]; bZ0 = bhh0[H_N + unit]; bN0 = bhh0[2 * H_N + unit];
    xR1 = bih1[unit]; xZ1 = bih1[H_N + unit]; xN1 = bih1[2 * H_N + unit];
    hR1 = bhh1[unit]; hZ1 = bhh1[H_N + unit]; hN1 = bhh1[2 * H_N + unit];
    hv0 = hx[(size_t)gbi * H_N + unit];
    hv1 = hx[(size_t)(B_N + gbi) * H_N + unit];
  }

  for (int t = 0; t <= T_N; ++t) {
    // ---- prefetch layer-0 gx for gate A (independent of barrier) ----
    float ir0 = 0, iz0 = 0, in0 = 0;
    if (t < T_N && tid < 128) {
      const float* p = gx + ((size_t)t * B_N + 8 * g + gb8) * G3 + 16 * j + gu;
      ir0 = p[0]; iz0 = p[H_N]; in0 = p[2 * H_N];
    }

    // ---- combined poll: lanes 0-31 flag0>=t, lanes 32-63 flag1>=t-1 ----
    if (t > 0) {
      if (tid < 64) {
        int* fp = (tid < 32) ? (flags0 + (8 * tid + g) * 16)
                             : (flags1 + (8 * (tid - 32) + g) * 16);
        const int need = (tid < 32) ? t : (t - 1);
        int spin = 0;
        for (;;) {
          int f = __hip_atomic_load(fp, __ATOMIC_RELAXED, __HIP_MEMORY_SCOPE_AGENT);
          if (__all(f >= need)) break;
          __builtin_amdgcn_s_sleep(1);
          if ((++spin & 1023) == 1023)   // hang guard; ~never fires
            __builtin_amdgcn_fence(__ATOMIC_ACQUIRE, "agent");
        }
      }
      __builtin_amdgcn_sched_barrier(0);
      __syncthreads();
    }

    // ---- stage h0_{t-1} and h1_{t-2} (fp16, coherent 8B loads) ----
    {
      unsigned long long* s0 = (unsigned long long*)(h0x + (size_t)((t - 1) & 1) * (B_N * H_N) + (size_t)(8 * g) * H_N);
      unsigned long long* s1 = (unsigned long long*)(h1x + (size_t)((t - 2) & 1) * (B_N * H_N) + (size_t)(8 * g) * H_N);
      unsigned long long* d0 = (unsigned long long*)sh0;
      unsigned long long* d1 = (unsigned long long*)sh1;
#pragma unroll
      for (int e = 0; e < 4; ++e) {
        d0[e * 256 + tid] = __hip_atomic_load(s0 + e * 256 + tid, __ATOMIC_RELAXED, __HIP_MEMORY_SCOPE_AGENT);
        d1[e * 256 + tid] = __hip_atomic_load(s1 + e * 256 + tid, __ATOMIC_RELAXED, __HIP_MEMORY_SCOPE_AGENT);
      }
    }
    __syncthreads();

    // ================= phase A: layer 0, h0_t =================
    if (t < T_N) {
      float acc[3][2][8];
#pragma unroll
      for (int q = 0; q < 3; ++q)
#pragma unroll
        for (int e = 0; e < 2; ++e)
#pragma unroll
          for (int bb = 0; bb < 8; ++bb) acc[q][e][bb] = 0.f;

#pragma unroll
      for (int bb = 0; bb < 8; ++bb) {
        uint4 u0 = *(const uint4*)&sh0[bb * 512 + 8 * s];
        uint4 u1 = *(const uint4*)&sh0[bb * 512 + 256 + 8 * s];
        f16x2 h[8] = {bch2(u0.x), bch2(u0.y), bch2(u0.z), bch2(u0.w),
                      bch2(u1.x), bch2(u1.y), bch2(u1.z), bch2(u1.w)};
#pragma unroll
        for (int e = 0; e < 2; ++e) {
          float ar = acc[0][e][bb], az = acc[1][e][bb], an = acc[2][e][bb];
#pragma unroll
          for (int c = 0; c < 8; ++c) {
            ar = fdot2_(wA[0][e][c], h[c], ar);
            az = fdot2_(wA[1][e][c], h[c], az);
            an = fdot2_(wA[2][e][c], h[c], an);
          }
          acc[0][e][bb] = ar; acc[1][e][bb] = az; acc[2][e][bb] = an;
        }
      }
#pragma unroll
      for (int q = 0; q < 3; ++q)
#pragma unroll
        for (int e = 0; e < 2; ++e)
#pragma unroll
          for (int bb = 0; bb < 8; ++bb)
            red[((2 * up + e) + 16 * (q * 8 + bb)) * 36 + s] = acc[q][e][bb];
      __syncthreads();

      if (tid < 128) {
        float sg[3];
#pragma unroll
        for (int q = 0; q < 3; ++q) {
          const float* rp = &red[(size_t)(gu + 16 * (q * 8 + gb8)) * 36];
          float4 a = *(const float4*)(rp + 0),  b4 = *(const float4*)(rp + 4);
          float4 c4 = *(const float4*)(rp + 8), d4 = *(const float4*)(rp + 12);
          float4 a2 = *(const float4*)(rp + 16), b2 = *(const float4*)(rp + 20);
          float4 c2 = *(const float4*)(rp + 24), d2 = *(const float4*)(rp + 28);
          sg[q] = (((a.x+a.y)+(a.z+a.w)) + ((b4.x+b4.y)+(b4.z+b4.w)))
                + (((c4.x+c4.y)+(c4.z+c4.w)) + ((d4.x+d4.y)+(d4.z+d4.w)))
                + (((a2.x+a2.y)+(a2.z+a2.w)) + ((b2.x+b2.y)+(b2.z+b2.w)))
                + (((c2.x+c2.y)+(c2.z+c2.w)) + ((d2.x+d2.y)+(d2.z+d2.w)));
        }
        float r = sigm_(ir0 + sg[0] + bR0);
        float z = sigm_(iz0 + sg[1] + bZ0);
        float n = tanhf(in0 + r * (sg[2] + bN0));
        float hy = n + z * (hv0 - n);
        hv0 = hy;
        pk[gb8 * 16 + gu] = __builtin_bit_cast(unsigned short, (f16)hy);
        if (t == T_N - 1) hT[(size_t)(8 * g + gb8) * H_N + 16 * j + gu] = hy;
      }
      __syncthreads();
      if (tid < 32) {   // coalesced coherent exchange store of h0_t
        const int bb = tid >> 2, qw = tid & 3;
        unsigned long long v = ((const unsigned long long*)pk)[bb * 4 + qw];
        unsigned long long* dp = (unsigned long long*)(h0x + (size_t)(t & 1) * (B_N * H_N) + (size_t)(8 * g + bb) * H_N + 16 * j) + qw;
        __hip_atomic_store(dp, v, __ATOMIC_RELAXED, __HIP_MEMORY_SCOPE_AGENT);
      }
      asm volatile("s_waitcnt vmcnt(0)" ::: "memory");
      __syncthreads();
      if (tid == 0)
        __hip_atomic_store(flags0 + bid * 16, t + 1, __ATOMIC_RELAXED, __HIP_MEMORY_SCOPE_AGENT);
    }

    // ================= phase B: layer 1, h1_{t-1} =================
    if (t > 0) {
      float accB[4][2][8];   // r(merged), z(merged), n_x, n_h
#pragma unroll
      for (int q = 0; q < 4; ++q)
#pragma unroll
        for (int e = 0; e < 2; ++e)
#pragma unroll
          for (int bb = 0; bb < 8; ++bb) accB[q][e][bb] = 0.f;

#pragma unroll
      for (int bb = 0; bb < 8; ++bb) {
        uint4 ux0 = *(const uint4*)&sh0[bb * 512 + 8 * s];
        uint4 ux1 = *(const uint4*)&sh0[bb * 512 + 256 + 8 * s];
        uint4 uh0 = *(const uint4*)&sh1[bb * 512 + 8 * s];
        uint4 uh1 = *(const uint4*)&sh1[bb * 512 + 256 + 8 * s];
        f16x2 xv[8] = {bch2(ux0.x), bch2(ux0.y), bch2(ux0.z), bch2(ux0.w),
                       bch2(ux1.x), bch2(ux1.y), bch2(ux1.z), bch2(ux1.w)};
        f16x2 hw[8] = {bch2(uh0.x), bch2(uh0.y), bch2(uh0.z), bch2(uh0.w),
                       bch2(uh1.x), bch2(uh1.y), bch2(uh1.z), bch2(uh1.w)};
#pragma unroll
        for (int e = 0; e < 2; ++e) {
          float ar = accB[0][e][bb], az = accB[1][e][bb];
          float anx = accB[2][e][bb], anh = accB[3][e][bb];
#pragma unroll
          for (int c = 0; c < 8; ++c) {
            ar  = fdot2_(wX[0][e][c], xv[c], ar);
            ar  = fdot2_(wH[0][e][c], hw[c], ar);
            az  = fdot2_(wX[1][e][c], xv[c], az);
            az  = fdot2_(wH[1][e][c], hw[c], az);
            anx = fdot2_(wX[2][e][c], xv[c], anx);
            anh = fdot2_(wH[2][e][c], hw[c], anh);
          }
          accB[0][e][bb] = ar;  accB[1][e][bb] = az;
          accB[2][e][bb] = anx; accB[3][e][bb] = anh;
        }
      }
#pragma unroll
      for (int q = 0; q < 4; ++q)
#pragma unroll
        for (int e = 0; e < 2; ++e)
#pragma unroll
          for (int bb = 0; bb < 8; ++bb)
            red[((2 * up + e) + 16 * (q * 8 + bb)) * 36 + s] = accB[q][e][bb];
      __syncthreads();

      float hyB = 0.f;
      if (tid < 128) {
        float sg[4];
#pragma unroll
        for (int q = 0; q < 4; ++q) {
          const float* rp = &red[(size_t)(gu + 16 * (q * 8 + gb8)) * 36];
          float4 a = *(const float4*)(rp + 0),  b4 = *(const float4*)(rp + 4);
          float4 c4 = *(const float4*)(rp + 8), d4 = *(const float4*)(rp + 12);
          float4 a2 = *(const float4*)(rp + 16), b2 = *(const float4*)(rp + 20);
          float4 c2 = *(const float4*)(rp + 24), d2 = *(const float4*)(rp + 28);
          sg[q] = (((a.x+a.y)+(a.z+a.w)) + ((b4.x+b4.y)+(b4.z+b4.w)))
                + (((c4.x+c4.y)+(c4.z+c4.w)) + ((d4.x+d4.y)+(d4.z+d4.w)))
                + (((a2.x+a2.y)+(a2.z+a2.w)) + ((b2.x+b2.y)+(b2.z+b2.w)))
                + (((c2.x+c2.y)+(c2.z+c2.w)) + ((d2.x+d2.y)+(d2.z+d2.w)));
        }
        float r = sigm_(sg[0] + xR1 + hR1);
        float z = sigm_(sg[1] + xZ1 + hZ1);
        float n = tanhf(sg[2] + xN1 + r * (sg[3] + hN1));
        hyB = n + z * (hv1 - n);
        hv1 = hyB;
        pk[gb8 * 16 + gu] = __builtin_bit_cast(unsigned short, (f16)hyB);
      }
      __syncthreads();
      if (tid < 32) {   // exchange store of h1_{t-1} -> slot (t-1)&1
        const int bb = tid >> 2, qw = tid & 3;
        unsigned long long v = ((const unsigned long long*)pk)[bb * 4 + qw];
        unsigned long long* dp = (unsigned long long*)(h1x + (size_t)((t - 1) & 1) * (B_N * H_N) + (size_t)(8 * g + bb) * H_N + 16 * j) + qw;
        __hip_atomic_store(dp, v, __ATOMIC_RELAXED, __HIP_MEMORY_SCOPE_AGENT);
      }
      asm volatile("s_waitcnt vmcnt(0)" ::: "memory");
      __syncthreads();
      if (tid == 0)
        __hip_atomic_store(flags1 + bid * 16, t, __ATOMIC_RELAXED, __HIP_MEMORY_SCOPE_AGENT);

      // deferred fp32 output stores (off the critical path)
      if (tid < 128) {
        out[((size_t)(t - 1) * B_N + 8 * g + gb8) * H_N + 16 * j + gu] = hyB;
        if (t == T_N)
          hT[(size_t)(B_N + 8 * g + gb8) * H_N + 16 * j + gu] = hyB;
      }
    }
  }
}

// ---------------------------------------------------------------------------
extern "C" void kernel_launch(void* const* d_in, const int* in_sizes, int n_in,
                              void* d_out, int out_size, void* d_ws, size_t ws_size,
                              hipStream_t stream)
{
  const float* x    = (const float*)d_in[0];
  const float* hx   = (const float*)d_in[1];
  const float* wih0 = (const float*)d_in[2];
  const float* whh0 = (const float*)d_in[3];
  const float* bih0 = (const float*)d_in[4];
  const float* bhh0 = (const float*)d_in[5];
  const float* wih1 = (const float*)d_in[6];
  const float* whh1 = (const float*)d_in[7];
  const float* bih1 = (const float*)d_in[8];
  const float* bhh1 = (const float*)d_in[9];
  float* out = (float*)d_out;            // [T*B*H] output, then [L*B*H] hT

  // workspace: gx0 [T*B*3H] fp32 | h0x 2*[B*H] f16 | h1x 2*[B*H] f16 | flags
  float* gxb = (float*)d_ws;
  f16*   h0x = (f16*)(gxb + (size_t)T_N * B_N * G3);
  f16*   h1x = h0x + 2 * B_N * H_N;
  int*   flags0 = (int*)(h1x + 2 * B_N * H_N);
  int*   flags1 = flags0 + NBLK * 16;

  hipMemsetAsync(flags0, 0, 2 * NBLK * 16 * sizeof(int), stream);
  pack_h_init<<<128, 256, 0, stream>>>(hx, h0x + B_N * H_N, h1x + B_N * H_N);

  dim3 gg(G3 / 64, (T_N * B_N) / 64);
  gemm_nt<<<gg, 256, 0, stream>>>(x, wih0, bih0, gxb, T_N * B_N, G3, I_N);

  gru_fused<<<NBLK, 256, 0, stream>>>(gxb, hx, wih1, whh0, whh1,
                                      bih1, bhh0, bhh1,
                                      out, out + (size_t)T_N * B_N * H_N,
                                      h0x, h1x, flags0, flags1);
}

// Round 6
// 8997.878 us; speedup vs baseline: 11.8141x; 1.1484x over previous
//
#include <hip/hip_runtime.h>
#include <cstdint>
#include <cstddef>

#define T_N 1024
#define B_N 64
#define I_N 512
#define H_N 512
#define G3  (3*H_N)
#define NBLK 256   // 8 groups (8 batches) x 32 blocks (16 units)

typedef _Float16 f16;
typedef _Float16 f16x2 __attribute__((ext_vector_type(2)));
typedef unsigned long long ull;

// exchange ring: data generation d lives in slot SLOT(d) with LSB tag TAG1(d)
#define SLOT(d) (((d)+2)&1)
#define TAG1(d) ((((d)+2)>>1)&1)

__device__ __forceinline__ f16x2 mkh2(float a, float b) {
  f16x2 v; v.x = (_Float16)a; v.y = (_Float16)b; return v;
}
__device__ __forceinline__ f16x2 bch2(unsigned int u) {
  return __builtin_bit_cast(f16x2, u);
}
__device__ __forceinline__ float fdot2_(f16x2 a, f16x2 b, float c) {
#if __has_builtin(__builtin_amdgcn_fdot2)
  return __builtin_amdgcn_fdot2(a, b, c, false);
#else
  return fmaf((float)a.x, (float)b.x, fmaf((float)a.y, (float)b.y, c));
#endif
}
__device__ __forceinline__ float sigm_(float x) { return 1.f / (1.f + __expf(-x)); }
__device__ __forceinline__ float tanhf_(float x) {
  float xx = fminf(15.f, fmaxf(-15.f, x));
  float e = __expf(2.f * xx);
  return (e - 1.f) / (e + 1.f);
}

// ---------------------------------------------------------------------------
// GEMM: C[m][n] = sum_k A[m][k]*W[n][k] + bias[n]   (layer-0 input gates)
// ---------------------------------------------------------------------------
__global__ __launch_bounds__(256) void gemm_nt(
    const float* __restrict__ A,
    const float* __restrict__ W,
    const float* __restrict__ bias,
    float* __restrict__ C,
    int M, int N, int K)
{
  __shared__ float As[32][68];
  __shared__ float Ws[32][68];
  const int tid = threadIdx.x;
  const int n0 = blockIdx.x * 64;
  const int m0 = blockIdx.y * 64;
  const int ty = tid >> 4;
  const int tx = tid & 15;

  float acc[4][4];
#pragma unroll
  for (int i = 0; i < 4; ++i)
#pragma unroll
    for (int jj = 0; jj < 4; ++jj) acc[i][jj] = 0.f;

  for (int k0 = 0; k0 < K; k0 += 32) {
#pragma unroll
    for (int i = 0; i < 2; ++i) {
      int idx = tid + i * 256;
      int r   = idx >> 3;
      int c4  = idx & 7;
      float4 va = *(const float4*)(A + (size_t)(m0 + r) * K + k0 + c4 * 4);
      As[c4*4+0][r] = va.x; As[c4*4+1][r] = va.y;
      As[c4*4+2][r] = va.z; As[c4*4+3][r] = va.w;
      float4 vw = *(const float4*)(W + (size_t)(n0 + r) * K + k0 + c4 * 4);
      Ws[c4*4+0][r] = vw.x; Ws[c4*4+1][r] = vw.y;
      Ws[c4*4+2][r] = vw.z; Ws[c4*4+3][r] = vw.w;
    }
    __syncthreads();
#pragma unroll
    for (int k = 0; k < 32; ++k) {
      float4 a = *(const float4*)&As[k][ty * 4];
      float4 w = *(const float4*)&Ws[k][tx * 4];
      acc[0][0] += a.x*w.x; acc[0][1] += a.x*w.y; acc[0][2] += a.x*w.z; acc[0][3] += a.x*w.w;
      acc[1][0] += a.y*w.x; acc[1][1] += a.y*w.y; acc[1][2] += a.y*w.z; acc[1][3] += a.y*w.w;
      acc[2][0] += a.z*w.x; acc[2][1] += a.z*w.y; acc[2][2] += a.z*w.z; acc[2][3] += a.z*w.w;
      acc[3][0] += a.w*w.x; acc[3][1] += a.w*w.y; acc[3][2] += a.w*w.z; acc[3][3] += a.w*w.w;
    }
    __syncthreads();
  }

  float4 bv = *(const float4*)(bias + n0 + tx * 4);
#pragma unroll
  for (int i = 0; i < 4; ++i) {
    int row = m0 + ty * 4 + i;
    float4 o;
    o.x = acc[i][0] + bv.x; o.y = acc[i][1] + bv.y;
    o.z = acc[i][2] + bv.z; o.w = acc[i][3] + bv.w;
    *(float4*)(C + (size_t)row * N + n0 + tx * 4) = o;
  }
}

// init: pack fp32 hx -> f16 exchange slot 1 with tag TAG1(-1)=0 (LSB cleared)
__global__ __launch_bounds__(256) void pack_h_init(
    const float* __restrict__ hx, f16* h0x, f16* h1x)
{
  int i = blockIdx.x * 256 + threadIdx.x;   // 0..32767
  unsigned short a = __builtin_bit_cast(unsigned short, (f16)hx[i]) & 0xFFFEu;
  unsigned short b = __builtin_bit_cast(unsigned short, (f16)hx[B_N * H_N + i]) & 0xFFFEu;
  ((unsigned short*)h0x)[B_N * H_N + i] = a;
  ((unsigned short*)h1x)[B_N * H_N + i] = b;
}

#define D4(acc, wv, vv)                      \
  acc = fdot2_(wv[0], bch2((vv).x), acc);    \
  acc = fdot2_(wv[1], bch2((vv).y), acc);    \
  acc = fdot2_(wv[2], bch2((vv).z), acc);    \
  acc = fdot2_(wv[3], bch2((vv).w), acc);

// ---------------------------------------------------------------------------
// Fused 2-layer pipelined persistent scan with self-certifying (LSB-tagged)
// fp16 h exchange: ONE IF round trip per step, no flags, no fences, no vmcnt.
// Per step: tagged stage -> single compute pass (A: h0_t partials, B: h1_{t-1}
// partials) -> one reduce -> gateA (waves 0-1) || gateB (waves 2-3) -> tagged
// stores. 3 barriers/step.
// ---------------------------------------------------------------------------
__global__ __launch_bounds__(256, 1) void gru_fused(
    const float* __restrict__ gx,    // [T][64][1536] layer-0 input gates
    const float* __restrict__ hx,    // [2][64][512] fp32 initial h
    const float* wih1, const float* whh0, const float* whh1,
    const float* bih1, const float* bhh0, const float* bhh1,
    float* __restrict__ out,         // [T][64][512]
    float* __restrict__ hT,          // [2][64][512]
    f16* h0x, f16* h1x)              // 2 x [64][512] f16 tagged rings
{
  __shared__ __align__(16) ull sh0q[1024];          // 8 KB h0_{t-1} (group)
  __shared__ __align__(16) ull sh1q[1024];          // 8 KB h1_{t-2}
  __shared__ float red[(384 + 512) * 20];           // 70 KB k-split partials
  __shared__ __align__(8) unsigned short pkA[128], pkB[128];

  const int tid = threadIdx.x;
  const int bid = blockIdx.x;
  const int g = bid & 7;        // batch group (8 batches)
  const int j = bid >> 3;       // block in group -> units 16j..16j+15
  const int u = tid >> 4;       // unit 0..15
  const int s = tid & 15;       // k-split 0..15 (covers k = 8s+128c, c<4)
  const ull M = 0x0001000100010001ULL;

  // ---- persistent fp16 weights in registers (144 VGPRs) ----
  f16x2 wA[3][4][4], wX[3][4][4], wH[3][4][4];
#pragma unroll
  for (int q = 0; q < 3; ++q) {
    const size_t row = (size_t)(q * H_N + 16 * j + u) * H_N;
    const float* pA = whh0 + row;
    const float* pX = wih1 + row;
    const float* pH = whh1 + row;
#pragma unroll
    for (int c = 0; c < 4; ++c)
#pragma unroll
      for (int d = 0; d < 4; ++d) {
        const int k = 8 * s + 128 * c + 2 * d;
        wA[q][c][d] = mkh2(pA[k], pA[k + 1]);
        wX[q][c][d] = mkh2(pX[k], pX[k + 1]);
        wH[q][c][d] = mkh2(pH[k], pH[k + 1]);
      }
  }

  // ---- gate identity: waves 0-1 = layer 0, waves 2-3 = layer 1 ----
  const int gl = tid & 127, gu = gl & 15, gb8 = gl >> 4;
  const bool isA = tid < 128;
  const int unit = 16 * j + gu, gbi = 8 * g + gb8;
  const float bRv = isA ? bhh0[unit]           : (bih1[unit] + bhh1[unit]);
  const float bZv = isA ? bhh0[H_N + unit]     : (bih1[H_N + unit] + bhh1[H_N + unit]);
  const float bNv = isA ? bhh0[2 * H_N + unit] : bih1[2 * H_N + unit];
  const float bDv = isA ? 0.f                  : bhh1[2 * H_N + unit];
  float hv = hx[(size_t)(isA ? 0 : B_N * H_N) + (size_t)gbi * H_N + unit];

  for (int t = 0; t <= T_N; ++t) {
    const bool runA = (t < T_N), runB = (t > 0);

    // layer-0 gx prefetch (HBM latency hides under the stage poll)
    float ir0 = 0, iz0 = 0, in0 = 0;
    if (runA && isA) {
      const float* p = gx + ((size_t)t * B_N + gbi) * G3 + unit;
      ir0 = p[0]; iz0 = p[H_N]; in0 = p[2 * H_N];
    }

    // ---- tagged stage: retry until every granule's LSBs match the tag ----
    const ull* s0 = (const ull*)h0x + (size_t)SLOT(t - 1) * 8192 + (size_t)(8 * g) * 128;
    const ull* s1 = (const ull*)h1x + (size_t)SLOT(t - 2) * 8192 + (size_t)(8 * g) * 128;
    const ull e0 = TAG1(t - 1) ? M : 0ULL;
    const ull e1 = TAG1(t - 2) ? M : 0ULL;
    ull v0[4], v1[4];
    bool k0[4] = {false, false, false, false};
    bool k1[4] = {!runB, !runB, !runB, !runB};
    for (;;) {
#pragma unroll
      for (int e = 0; e < 4; ++e) {   // issue all pending loads first
        if (!k0[e]) v0[e] = __hip_atomic_load(s0 + e * 256 + tid, __ATOMIC_RELAXED, __HIP_MEMORY_SCOPE_AGENT);
        if (!k1[e]) v1[e] = __hip_atomic_load(s1 + e * 256 + tid, __ATOMIC_RELAXED, __HIP_MEMORY_SCOPE_AGENT);
      }
      bool all = true;
#pragma unroll
      for (int e = 0; e < 4; ++e) {
        if (!k0[e]) k0[e] = ((v0[e] & M) == e0);
        if (!k1[e]) k1[e] = ((v1[e] & M) == e1);
        all = all && k0[e] && k1[e];
      }
      if (__all(all)) break;
      __builtin_amdgcn_s_sleep(1);
    }
#pragma unroll
    for (int e = 0; e < 4; ++e) {
      sh0q[e * 256 + tid] = v0[e];
      if (runB) sh1q[e * 256 + tid] = v1[e];
    }
    __syncthreads();

    // ---- single compute pass: A (384 dot2) + B (768 dot2) ----
    float aA[3][8], aB[4][8];
#pragma unroll
    for (int q = 0; q < 3; ++q)
#pragma unroll
      for (int bb = 0; bb < 8; ++bb) aA[q][bb] = 0.f;
#pragma unroll
    for (int q = 0; q < 4; ++q)
#pragma unroll
      for (int bb = 0; bb < 8; ++bb) aB[q][bb] = 0.f;

    const uint4* x4 = (const uint4*)sh0q;
    const uint4* h4 = (const uint4*)sh1q;
#pragma unroll
    for (int bb = 0; bb < 8; ++bb) {
      uint4 xc[4], hc[4];
#pragma unroll
      for (int c = 0; c < 4; ++c) xc[c] = x4[bb * 64 + s + 16 * c];
      if (runB) {
#pragma unroll
        for (int c = 0; c < 4; ++c) hc[c] = h4[bb * 64 + s + 16 * c];
      }
      if (runA) {
#pragma unroll
        for (int q = 0; q < 3; ++q) {
          float a = aA[q][bb];
#pragma unroll
          for (int c = 0; c < 4; ++c) { D4(a, wA[q][c], xc[c]); }
          aA[q][bb] = a;
        }
      }
      if (runB) {
        float a0 = aB[0][bb], a1 = aB[1][bb], a2 = aB[2][bb], a3 = aB[3][bb];
#pragma unroll
        for (int c = 0; c < 4; ++c) {
          D4(a0, wX[0][c], xc[c]); D4(a0, wH[0][c], hc[c]);
          D4(a1, wX[1][c], xc[c]); D4(a1, wH[1][c], hc[c]);
          D4(a2, wX[2][c], xc[c]);
          D4(a3, wH[2][c], hc[c]);
        }
        aB[0][bb] = a0; aB[1][bb] = a1; aB[2][bb] = a2; aB[3][bb] = a3;
      }
    }

    // ---- one reduce: write k-split partials (column-swizzled) ----
    const int col = (s + u) & 15;
    if (runA) {
#pragma unroll
      for (int q = 0; q < 3; ++q)
#pragma unroll
        for (int bb = 0; bb < 8; ++bb)
          red[(size_t)(u + 16 * (q * 8 + bb)) * 20 + col] = aA[q][bb];
    }
    if (runB) {
#pragma unroll
      for (int q = 0; q < 4; ++q)
#pragma unroll
        for (int bb = 0; bb < 8; ++bb)
          red[(size_t)(384 + u + 16 * (q * 8 + bb)) * 20 + col] = aB[q][bb];
    }
    __syncthreads();

    // ---- gates in parallel: A on waves 0-1, B on waves 2-3 ----
    if (isA) {
      if (runA) {
        float sg[3];
#pragma unroll
        for (int q = 0; q < 3; ++q) {
          const float* rp = &red[(size_t)(gu + 16 * (q * 8 + gb8)) * 20];
          float4 a = *(const float4*)rp,        b4 = *(const float4*)(rp + 4);
          float4 c4 = *(const float4*)(rp + 8), d4 = *(const float4*)(rp + 12);
          sg[q] = (((a.x + a.y) + (a.z + a.w)) + ((b4.x + b4.y) + (b4.z + b4.w)))
                + (((c4.x + c4.y) + (c4.z + c4.w)) + ((d4.x + d4.y) + (d4.z + d4.w)));
        }
        float r = sigm_(ir0 + sg[0] + bRv);
        float z = sigm_(iz0 + sg[1] + bZv);
        float n = tanhf_(in0 + r * (sg[2] + bNv));
        float hy = n + z * (hv - n); hv = hy;
        pkA[gl] = __builtin_bit_cast(unsigned short, (f16)hy);
        if (t == T_N - 1) hT[(size_t)gbi * H_N + unit] = hy;
      }
    } else {
      if (runB) {
        float sg[4];
#pragma unroll
        for (int q = 0; q < 4; ++q) {
          const float* rp = &red[(size_t)(384 + gu + 16 * (q * 8 + gb8)) * 20];
          float4 a = *(const float4*)rp,        b4 = *(const float4*)(rp + 4);
          float4 c4 = *(const float4*)(rp + 8), d4 = *(const float4*)(rp + 12);
          sg[q] = (((a.x + a.y) + (a.z + a.w)) + ((b4.x + b4.y) + (b4.z + b4.w)))
                + (((c4.x + c4.y) + (c4.z + c4.w)) + ((d4.x + d4.y) + (d4.z + d4.w)));
        }
        float r = sigm_(sg[0] + bRv);
        float z = sigm_(sg[1] + bZv);
        float n = tanhf_(sg[2] + bNv + r * (sg[3] + bDv));
        float hy = n + z * (hv - n); hv = hy;
        pkB[gl] = __builtin_bit_cast(unsigned short, (f16)hy);
        out[((size_t)(t - 1) * B_N + gbi) * H_N + unit] = hy;
        if (t == T_N) hT[(size_t)(B_N + gbi) * H_N + unit] = hy;
      }
    }
    __syncthreads();

    // ---- tagged exchange stores (fire-and-forget; tags ARE the flag) ----
    if (tid < 32) {
      if (runA) {
        ull v = ((const ull*)pkA)[tid];
        v = (v & ~M) | (TAG1(t) ? M : 0ULL);
        ull* dp = (ull*)h0x + (size_t)SLOT(t) * 8192
                + (size_t)(8 * g + (tid >> 2)) * 128 + 4 * j + (tid & 3);
        __hip_atomic_store(dp, v, __ATOMIC_RELAXED, __HIP_MEMORY_SCOPE_AGENT);
      }
    } else if (tid < 64) {
      if (runB) {
        const int l = tid - 32;
        ull v = ((const ull*)pkB)[l];
        v = (v & ~M) | (TAG1(t - 1) ? M : 0ULL);
        ull* dp = (ull*)h1x + (size_t)SLOT(t - 1) * 8192
                + (size_t)(8 * g + (l >> 2)) * 128 + 4 * j + (l & 3);
        __hip_atomic_store(dp, v, __ATOMIC_RELAXED, __HIP_MEMORY_SCOPE_AGENT);
      }
    }
  }
}

// ---------------------------------------------------------------------------
extern "C" void kernel_launch(void* const* d_in, const int* in_sizes, int n_in,
                              void* d_out, int out_size, void* d_ws, size_t ws_size,
                              hipStream_t stream)
{
  const float* x    = (const float*)d_in[0];
  const float* hx   = (const float*)d_in[1];
  const float* wih0 = (const float*)d_in[2];
  const float* whh0 = (const float*)d_in[3];
  const float* bih0 = (const float*)d_in[4];
  const float* bhh0 = (const float*)d_in[5];
  const float* wih1 = (const float*)d_in[6];
  const float* whh1 = (const float*)d_in[7];
  const float* bih1 = (const float*)d_in[8];
  const float* bhh1 = (const float*)d_in[9];
  float* out = (float*)d_out;            // [T*B*H] output, then [L*B*H] hT

  // workspace: gx [T*B*3H] fp32 | h0x 2*[B*H] f16 | h1x 2*[B*H] f16
  float* gxb = (float*)d_ws;
  f16*   h0x = (f16*)(gxb + (size_t)T_N * B_N * G3);
  f16*   h1x = h0x + 2 * B_N * H_N;

  pack_h_init<<<128, 256, 0, stream>>>(hx, h0x, h1x);

  dim3 gg(G3 / 64, (T_N * B_N) / 64);
  gemm_nt<<<gg, 256, 0, stream>>>(x, wih0, bih0, gxb, T_N * B_N, G3, I_N);

  gru_fused<<<NBLK, 256, 0, stream>>>(gxb, hx, wih1, whh0, whh1,
                                      bih1, bhh0, bhh1,
                                      out, out + (size_t)T_N * B_N * H_N,
                                      h0x, h1x);
}